// Round 1
// baseline (186.065 us; speedup 1.0000x reference)
//
#include <hip/hip_runtime.h>

#define TILE 16
#define HSZ 256
#define WSZ 256
#define NFC 64

// One 16x16 output tile per 256-thread block.
// Stage A: compute per-pixel 3x3 filters (9 channels) from pixel-unshuffled i_t.
// Stage B: apply filters to all 64 channels of h, 4 channels per LDS pass.
__global__ __launch_bounds__(256, 2) void fused_dynfilter(
    const float* __restrict__ hbuf,
    const float* __restrict__ i_t,
    const float* __restrict__ wbuf,
    const float* __restrict__ bias,
    float* __restrict__ out)
{
    // Stage A: xs4[ic4*324 + sp] (12*324 float4 = 62208 B)
    // Stage B: hs4[sp] (324 float4) — overlaid, separated by barriers.
    __shared__ __align__(16) float smem[15552];
    float4* xs4 = (float4*)smem;

    const int tid = threadIdx.x;
    const int px = tid & 15;
    const int py = tid >> 4;
    const int X0 = blockIdx.x * TILE;
    const int Y0 = blockIdx.y * TILE;
    const int b  = blockIdx.z;

    // ---------------- Stage A: stage unshuffled guidance tile (18x18 halo) ----------------
    // x-channel (c3*16 + fy*4 + fx)  <->  ic4 = c3*4 + fy, float4 lane j = fx.
    // x[b, ch, Y, X] = i_t[b, c3, 4Y+fy, 4X+fx]; fx 0..3 is one aligned float4 of i_t.
    const float* itb = i_t + (size_t)b * 3 * 1024 * 1024;
    for (int v = tid; v < 3888; v += 256) {
        int sp = v / 12;
        int t  = v - sp * 12;          // t == ic4 == c3*4 + fy
        int c3 = t >> 2;
        int fy = t & 3;
        int ly = sp / 18;
        int lx = sp - ly * 18;
        int Y = Y0 - 1 + ly;
        int X = X0 - 1 + lx;
        float4 val = make_float4(0.f, 0.f, 0.f, 0.f);
        if (Y >= 0 && Y < HSZ && X >= 0 && X < WSZ) {
            val = *(const float4*)(itb + ((size_t)c3 * 1024 + (4 * Y + fy)) * 1024 + 4 * X);
        }
        xs4[t * 324 + sp] = val;
    }
    __syncthreads();

    // ---------------- Stage A compute: 9 filter channels for this pixel ----------------
    float acc[9];
#pragma unroll
    for (int oc = 0; oc < 9; ++oc) acc[oc] = bias[oc];

#pragma unroll 1
    for (int ky = 0; ky < 3; ++ky) {
#pragma unroll 1
        for (int kx = 0; kx < 3; ++kx) {
            const int sp = (py + ky) * 18 + (px + kx);
            const int kk = ky * 3 + kx;
#pragma unroll
            for (int ic4 = 0; ic4 < 12; ++ic4) {
                float4 v = xs4[ic4 * 324 + sp];
                const int chb = ((ic4 >> 2) << 4) + ((ic4 & 3) << 2);  // c3*16 + fy*4
                const float* wp = wbuf + (size_t)chb * 9 + kk;          // + fx*9 + oc*432
                const float vv[4] = {v.x, v.y, v.z, v.w};
#pragma unroll
                for (int j = 0; j < 4; ++j) {
#pragma unroll
                    for (int oc = 0; oc < 9; ++oc) {
                        acc[oc] = fmaf(vv[j], wp[j * 9 + (size_t)oc * 432], acc[oc]);
                    }
                }
            }
        }
    }

    float flt[9];
#pragma unroll
    for (int oc = 0; oc < 9; ++oc) flt[oc] = fmaxf(acc[oc], 0.f);

    // ---------------- Stage B: dynamic conv over h, 4 channels per pass ----------------
    float4* hs4 = (float4*)smem;
#pragma unroll 1
    for (int cg = 0; cg < 16; ++cg) {
        __syncthreads();   // previous reads of smem complete
        const float* hp = hbuf + ((size_t)b * NFC + cg * 4) * HSZ * WSZ;
        for (int idx = tid; idx < 1296; idx += 256) {
            int c  = idx / 324;           // channel-major loop -> coalesced global reads
            int sp = idx - c * 324;
            int ly = sp / 18;
            int lx = sp - ly * 18;
            int Y = Y0 - 1 + ly;
            int X = X0 - 1 + lx;
            float vv = 0.f;
            if (Y >= 0 && Y < HSZ && X >= 0 && X < WSZ)
                vv = hp[(size_t)c * HSZ * WSZ + (size_t)Y * WSZ + X];
            smem[sp * 4 + c] = vv;
        }
        __syncthreads();

        float s0 = 0.f, s1 = 0.f, s2 = 0.f, s3 = 0.f;
#pragma unroll
        for (int ky = 0; ky < 3; ++ky) {
#pragma unroll
            for (int kx = 0; kx < 3; ++kx) {
                float4 v = hs4[(py + ky) * 18 + (px + kx)];
                float f = flt[ky * 3 + kx];
                s0 = fmaf(v.x, f, s0);
                s1 = fmaf(v.y, f, s1);
                s2 = fmaf(v.z, f, s2);
                s3 = fmaf(v.w, f, s3);
            }
        }
        size_t o = (((size_t)b * NFC + cg * 4) * HSZ + (Y0 + py)) * WSZ + (X0 + px);
        out[o]                           = s0;
        out[o + (size_t)HSZ * WSZ]       = s1;
        out[o + (size_t)2 * HSZ * WSZ]   = s2;
        out[o + (size_t)3 * HSZ * WSZ]   = s3;
    }
}

extern "C" void kernel_launch(void* const* d_in, const int* in_sizes, int n_in,
                              void* d_out, int out_size, void* d_ws, size_t ws_size,
                              hipStream_t stream) {
    const float* h      = (const float*)d_in[0];
    const float* i_t    = (const float*)d_in[1];
    const float* conv_w = (const float*)d_in[2];
    const float* conv_b = (const float*)d_in[3];
    float* out = (float*)d_out;

    const int B = in_sizes[0] / (NFC * HSZ * WSZ);
    dim3 grid(WSZ / TILE, HSZ / TILE, B);
    fused_dynfilter<<<grid, 256, 0, stream>>>(h, i_t, conv_w, conv_b, out);
}